// Round 8
// baseline (145.570 us; speedup 1.0000x reference)
//
#include <hip/hip_runtime.h>
#include <stdint.h>

// S=4096, D=64.  out = (t * floor(t*rr)/R) @ V,  t = (QK^T*8) * dropout_keep/0.9
// R8 = R7 (async global_load_lds staging of u, wave-private double-buffered LDS)
// + THE FIX: explicit `s_waitcnt vmcnt(0)` before each tile's u ds_read.
// global_load_lds completion is vmcnt-tracked; R7 only waited lgkmcnt -> race
// (stale u, absmax 5e-2). The drain sits before this tile's prefetch issues,
// so the 1-tile-deep pipeline is preserved; it also covers the prologue DMA.

#define S 4096
#define D 64
#define NCHUNK 16             // grid = 64 i-blocks * 16 chunks = 1024 blocks
#define JCHUNK (S / NCHUNK)   // 256
#define NTILES (JCHUNK / 64)  // 4
#define LDP 72                // pb row pitch in shorts
#define KSCALE (8.0f / 0.9f)

typedef float f32x4 __attribute__((ext_vector_type(4)));
typedef short s16x8 __attribute__((ext_vector_type(8)));
typedef unsigned short u16x4 __attribute__((ext_vector_type(4)));
typedef const __attribute__((address_space(1))) unsigned g_u32;
typedef __attribute__((address_space(3))) unsigned lds_u32;

__device__ inline unsigned short f2bf(float f) {
    union { float f; unsigned u; } v; v.f = f;
    unsigned r = v.u + 0x7fffu + ((v.u >> 16) & 1u);
    return (unsigned short)(r >> 16);
}

// ---- prep: Q->bf16, K->bf16*KSCALE (blocks 0..511), V->V^T (512..575) ----
__global__ void prep_all(const float* __restrict__ Q,
                         const float* __restrict__ Kf,
                         const float* __restrict__ V,
                         short* __restrict__ Qbf, short* __restrict__ Kbf,
                         short* __restrict__ VTbf, int* __restrict__ sumr) {
    __shared__ short tile[64 * 68];
    const int b   = blockIdx.x;
    const int tid = threadIdx.x;
    if (b == 0 && tid == 0) *sumr = 0;

    if (b < 512) {
        const int idx = b * 256 + tid;               // 131072 float4 slots
        if (idx < 65536) {
            float4 v = ((const float4*)Q)[idx];
            u16x4 o; o[0] = f2bf(v.x); o[1] = f2bf(v.y); o[2] = f2bf(v.z); o[3] = f2bf(v.w);
            ((u16x4*)Qbf)[idx] = o;
        } else {
            const int k = idx - 65536;
            float4 v = ((const float4*)Kf)[k];
            u16x4 o; o[0] = f2bf(v.x * KSCALE); o[1] = f2bf(v.y * KSCALE);
                     o[2] = f2bf(v.z * KSCALE); o[3] = f2bf(v.w * KSCALE);
            ((u16x4*)Kbf)[k] = o;
        }
    } else {
        const int j0 = (b - 512) * 64;
#pragma unroll
        for (int it = 0; it < 4; ++it) {
            const int f4 = tid + it * 256;
            const int row = f4 >> 4, c4 = (f4 & 15) * 4;
            float4 v = *(const float4*)&V[(size_t)(j0 + row) * D + c4];
            tile[(c4 + 0) * 68 + row] = (short)f2bf(v.x);
            tile[(c4 + 1) * 68 + row] = (short)f2bf(v.y);
            tile[(c4 + 2) * 68 + row] = (short)f2bf(v.z);
            tile[(c4 + 3) * 68 + row] = (short)f2bf(v.w);
        }
        __syncthreads();
#pragma unroll
        for (int it = 0; it < 4; ++it) {
            const int f4 = tid + it * 256;
            const int d = f4 >> 4, o4 = (f4 & 15) * 4;
            u16x4 w = *(const u16x4*)&tile[d * 68 + o4];
            *(u16x4*)&VTbf[(size_t)d * S + j0 + o4] = w;
        }
    }
}

// stage one wave's 16x64 fp32 u-tile into wave-private LDS (row-major, 4KB)
// lane writes land at lbase_bytes + lane*16 per issue: row q*4+lane/16,
// col (lane&15)*4 -> exactly row-major [16][64].
__device__ __forceinline__ void dma_u_tile(const float* __restrict__ g0,
                                           float* lbase, int lane) {
#pragma unroll
    for (int q = 0; q < 4; ++q) {
        const float* g = g0 + (size_t)(q * 4 + (lane >> 4)) * S + (lane & 15) * 4;
        __builtin_amdgcn_global_load_lds((g_u32*)g, (lds_u32*)(lbase + q * 256), 16, 0, 0);
    }
}

// ---- main: barrier-free, reg-pipelined K/V, DMA-pipelined u ----
__launch_bounds__(256, 2)
__global__ void fused_main(const short* __restrict__ Qbf,
                           const short* __restrict__ Kbf,
                           const short* __restrict__ VTbf,
                           const float* __restrict__ Ud,
                           const float* __restrict__ RR,
                           float* __restrict__ Opart,            // [NCHUNK][S][D]
                           int* __restrict__ sumr)
{
    __shared__ float uld[2][4][16 * 64];   // [buf][wave][row*64+col], 32KB
    __shared__ short pb[4 * 16 * LDP];
    __shared__ int red[4];

    const int tid  = threadIdx.x;
    const int w    = tid >> 6;
    const int lane = tid & 63;
    const int quad = lane >> 4;
    const int n16  = lane & 15;

    const int ib  = blockIdx.x & 63;
    const int ic  = blockIdx.x >> 6;
    const int i0w = ib * 64 + w * 16;
    const int jbase = ic * JCHUNK;

    const float* uwavebase = Ud + (size_t)i0w * S;   // this wave's 16 u rows

    s16x8 aQ[2];
#pragma unroll
    for (int ks = 0; ks < 2; ++ks)
        aQ[ks] = *(const s16x8*)&Qbf[(size_t)(i0w + n16) * D + ks * 32 + quad * 8];

    float rr[4];
#pragma unroll
    for (int rg = 0; rg < 4; ++rg) rr[rg] = RR[i0w + quad * 4 + rg];

    f32x4 accO[4];
#pragma unroll
    for (int ds = 0; ds < 4; ++ds) accO[ds] = (f32x4){0.f, 0.f, 0.f, 0.f};

    float lsum = 0.f;                 // r are small integers; fp32 sum exact
    short* pw = pb + w * 16 * LDP;

    s16x8 kf[2][8];      // K-frags, register double-buffered
    s16x8 vf[8];         // V-frags, single-buffered (in-tile slack)

    // prologue: DMA u(tile0) + K-frags(tile0)
    dma_u_tile(uwavebase + jbase, &uld[0][w][0], lane);
#pragma unroll
    for (int e = 0; e < 8; ++e) {
        const int cs = e >> 1, ks = e & 1;
        kf[0][e] = *(const s16x8*)&Kbf[(size_t)(jbase + cs * 16 + n16) * D + ks * 32 + quad * 8];
    }

#pragma unroll
    for (int jt = 0; jt < NTILES; ++jt) {
        const int bu = jt & 1;
        const int nb = bu ^ 1;
        const int j0 = jbase + jt * 64;

        // (a) THE FIX: drain vmem so DMA(jt) has landed in LDS before we read.
        //     Everything outstanding here was issued >= 1 tile ago (kf(jt)
        //     would be waited at QK anyway); this tile's prefetches are not
        //     yet issued, so the pipeline depth is untouched.
        __asm__ volatile("s_waitcnt vmcnt(0)" ::: "memory");
        __builtin_amdgcn_wave_barrier();

        //     u(jt): LDS -> regs, quad-swizzled order (2-way banks = free)
        float uv[16];
        {
            const float* uw = &uld[bu][w][0];
#pragma unroll
            for (int c = 0; c < 4; ++c) {
                const int cs = (c + quad) & 3;
#pragma unroll
                for (int rg = 0; rg < 4; ++rg)
                    uv[cs * 4 + rg] = uw[(quad * 4 + rg) * 64 + cs * 16 + n16];
            }
        }

        // (b) async DMA u(jt+1) into the other buffer
        if (jt + 1 < NTILES)
            dma_u_tile(uwavebase + j0 + 64, &uld[nb][w][0], lane);

        // (c) V-frags for THIS tile (consumed at tile end)
#pragma unroll
        for (int e = 0; e < 8; ++e) {
            const int ksj = e >> 2, ds = e & 3;
            vf[e] = *(const s16x8*)&VTbf[(size_t)(ds * 16 + n16) * S + j0 + ksj * 32 + quad * 8];
        }

        // (d) K-frags for NEXT tile
        if (jt + 1 < NTILES) {
#pragma unroll
            for (int e = 0; e < 8; ++e) {
                const int cs = e >> 1, ks = e & 1;
                kf[nb][e] = *(const s16x8*)&Kbf[(size_t)(j0 + 64 + cs * 16 + n16) * D + ks * 32 + quad * 8];
            }
        }

        // (e) QK^T on current K buffer
        f32x4 accqk[4];
#pragma unroll
        for (int cs = 0; cs < 4; ++cs) {
            f32x4 acc = (f32x4){0.f, 0.f, 0.f, 0.f};
#pragma unroll
            for (int ks = 0; ks < 2; ++ks)
                acc = __builtin_amdgcn_mfma_f32_16x16x32_bf16(aQ[ks], kf[bu][cs * 2 + ks], acc, 0, 0, 0);
            accqk[cs] = acc;
        }

        // (f) epilogue: dropout + floor (pure VALU, u already in regs)
#pragma unroll
        for (int cs = 0; cs < 4; ++cs) {
#pragma unroll
            for (int rg = 0; rg < 4; ++rg) {
                const float t = (uv[cs * 4 + rg] >= 0.1f) ? accqk[cs][rg] : 0.0f;
                const float r = floorf(t * rr[rg]);
                lsum += r;
                pw[(quad * 4 + rg) * LDP + cs * 16 + n16] = (short)f2bf(t * r);
            }
        }

        // (g) within-wave LDS drain for pb
        __builtin_amdgcn_wave_barrier();
        __asm__ volatile("s_waitcnt lgkmcnt(0)" ::: "memory");
        __builtin_amdgcn_wave_barrier();

        // (h) PV
#pragma unroll
        for (int ksj = 0; ksj < 2; ++ksj) {
            s16x8 aP = *(const s16x8*)&pw[n16 * LDP + ksj * 32 + quad * 8];
#pragma unroll
            for (int ds = 0; ds < 4; ++ds)
                accO[ds] = __builtin_amdgcn_mfma_f32_16x16x32_bf16(aP, vf[ksj * 4 + ds], accO[ds], 0, 0, 0);
        }
        __builtin_amdgcn_wave_barrier();   // pb reuse fence
    }

    // deterministic partial stores (full 64B segments)
    float* op = Opart + (size_t)ic * S * D;
#pragma unroll
    for (int ds = 0; ds < 4; ++ds) {
        const int d = ds * 16 + n16;
#pragma unroll
        for (int rg = 0; rg < 4; ++rg) {
            const int i = i0w + quad * 4 + rg;
            op[(size_t)i * D + d] = accO[ds][rg];
        }
    }

    // sum(r): wave shuffle -> LDS -> one int atomic per block
    for (int off = 32; off; off >>= 1) lsum += __shfl_down(lsum, off);
    if (lane == 0) red[w] = (int)lsum;
    __syncthreads();
    if (tid == 0) atomicAdd(sumr, red[0] + red[1] + red[2] + red[3]);
}

// ---- reduce partials over NCHUNK + apply 1/R ----
__global__ void reduce_out(const float* __restrict__ Opart,
                           const int* __restrict__ sumr,
                           float* __restrict__ out) {
    const int idx = blockIdx.x * 256 + threadIdx.x;   // 65536 float4 groups
    const float invR = 1.0f / (float)(*sumr);         // |R| < 2^24: exact
    float sx = 0.f, sy = 0.f, sz = 0.f, sw = 0.f;
#pragma unroll
    for (int c = 0; c < NCHUNK; ++c) {
        const float4 v = ((const float4*)(Opart + (size_t)c * S * D))[idx];
        sx += v.x; sy += v.y; sz += v.z; sw += v.w;
    }
    float4 o; o.x = sx * invR; o.y = sy * invR; o.z = sz * invR; o.w = sw * invR;
    ((float4*)out)[idx] = o;
}

extern "C" void kernel_launch(void* const* d_in, const int* in_sizes, int n_in,
                              void* d_out, int out_size, void* d_ws, size_t ws_size,
                              hipStream_t stream) {
    (void)in_sizes; (void)n_in; (void)out_size; (void)ws_size;
    const float* Q  = (const float*)d_in[0];
    const float* Kf = (const float*)d_in[1];
    const float* V  = (const float*)d_in[2];
    const float* Ud = (const float*)d_in[3];
    const float* RR = (const float*)d_in[4];
    float* out = (float*)d_out;

    // ws layout: Opart 16MB | Qbf 512KB | Kbf 512KB | VTbf 512KB | sumr
    char* ws = (char*)d_ws;
    float* Opart = (float*)ws;                                  // 16 MB
    short* Qbf  = (short*)(ws + (16u << 20));
    short* Kbf  = (short*)(ws + (16u << 20) + (512u << 10));
    short* VTbf = (short*)(ws + (16u << 20) + (1024u << 10));
    int*   sumr = (int*)  (ws + (16u << 20) + (1536u << 10));

    prep_all<<<dim3(576), dim3(256), 0, stream>>>(Q, Kf, V, Qbf, Kbf, VTbf, sumr);
    fused_main<<<dim3(64 * NCHUNK), dim3(256), 0, stream>>>(
        Qbf, Kbf, VTbf, Ud, RR, Opart, sumr);
    reduce_out<<<dim3(256), dim3(256), 0, stream>>>(Opart, sumr, out);
}